// Round 2
// baseline (1603.871 us; speedup 1.0000x reference)
//
#include <hip/hip_runtime.h>
#include <hip/hip_bf16.h>
#include <math.h>

// Problem constants
#define B_    2
#define C_    3
#define DDIM  160
#define HDIM  160
#define WDIM  160
#define DHW   (DDIM*HDIM*WDIM)      // 4,096,000
#define NVOX  (B_*DHW)              // 8,192,000
#define NGRP  (NVOX/4)              // 2,048,000 float4 groups
#define ITERS 8

#define SMOOTHF 1e-5
#define EPSF    1e-6
#define W_CL    0.5

// Reduction partials
#define NB1 1024
#define NQ1 10
#define NB2 1024
#define NQ2 4

// ws layout (bytes)
#define OFF_P1 0
#define OFF_P2 (NB1*NQ1*8)                 // 81,920
#define HEADER_BYTES 131072                // 128 KiB, 16B aligned

// ---------------- reduction helpers ----------------

__device__ inline double wave_reduce(double v) {
    #pragma unroll
    for (int off = 32; off > 0; off >>= 1)
        v += __shfl_down(v, off, 64);
    return v;
}

// block = 256 threads (4 waves). Reduces vals[0..nq) across block; thread 0
// writes nq doubles to out.
template<int NQ>
__device__ inline void block_reduce_store(double* vals, double* out) {
    __shared__ double smem[NQ][4];
    int lane = threadIdx.x & 63;
    int wid  = threadIdx.x >> 6;
    #pragma unroll
    for (int q = 0; q < NQ; ++q) {
        double v = wave_reduce(vals[q]);
        if (lane == 0) smem[q][wid] = v;
    }
    __syncthreads();
    if (threadIdx.x == 0) {
        #pragma unroll
        for (int q = 0; q < NQ; ++q)
            out[q] = smem[q][0] + smem[q][1] + smem[q][2] + smem[q][3];
    }
}

// ---------------- pass 1: softmax / CE / dice partials / p_v, y_v ----------------

__global__ void init_kernel(const float* __restrict__ logits,
                            const int*   __restrict__ target,
                            float* __restrict__ porig,
                            float* __restrict__ pskel,
                            float* __restrict__ yskel,
                            double* __restrict__ partials)
{
    double acc[NQ1];
    #pragma unroll
    for (int q = 0; q < NQ1; ++q) acc[q] = 0.0;
    // acc: 0=ce, 1..3=intersect_c, 4..6=pred_sum_c, 7..9=targ_sum_c

    int tid = blockIdx.x * blockDim.x + threadIdx.x;
    int stride = gridDim.x * blockDim.x;
    for (int g = tid; g < NGRP; g += stride) {
        int i = g * 4;
        int b = i / DHW;                 // groups never straddle batches (DHW%4==0)
        int s = i - b * DHW;
        const float* base = logits + (size_t)b * (C_ * DHW) + s;
        float4 l0 = *(const float4*)(base);
        float4 l1 = *(const float4*)(base + DHW);
        float4 l2 = *(const float4*)(base + 2 * DHW);
        int4 tg = *(const int4*)(target + i);

        float pv[4], yv[4];
        const float* a0 = (const float*)&l0;
        const float* a1 = (const float*)&l1;
        const float* a2 = (const float*)&l2;
        const int*   tt = (const int*)&tg;
        #pragma unroll
        for (int j = 0; j < 4; ++j) {
            float x0 = a0[j], x1 = a1[j], x2 = a2[j];
            float m  = fmaxf(x0, fmaxf(x1, x2));
            float e0 = expf(x0 - m), e1 = expf(x1 - m), e2 = expf(x2 - m);
            float sum = e0 + e1 + e2;
            float inv = 1.0f / sum;
            float q0 = e0 * inv, q1 = e1 * inv, q2 = e2 * inv;
            int t = tt[j];
            float lt = (t == 0) ? x0 : ((t == 1) ? x1 : x2);
            float logp_t = (lt - m) - logf(sum);
            acc[0] += (double)(-logp_t);
            acc[4] += (double)q0; acc[5] += (double)q1; acc[6] += (double)q2;
            if (t == 0)      { acc[1] += (double)q0; acc[7] += 1.0; }
            else if (t == 1) { acc[2] += (double)q1; acc[8] += 1.0; }
            else             { acc[3] += (double)q2; acc[9] += 1.0; }
            float p = 1.0f - q0;
            p = fminf(fmaxf(p, 0.0f), 1.0f);
            pv[j] = p;
            yv[j] = (t != 0) ? 1.0f : 0.0f;
        }
        *(float4*)(porig + i) = make_float4(pv[0], pv[1], pv[2], pv[3]);
        *(float4*)(pskel + i) = make_float4(pv[0], pv[1], pv[2], pv[3]);
        *(float4*)(yskel + i) = make_float4(yv[0], yv[1], yv[2], yv[3]);
    }
    block_reduce_store<NQ1>(acc, partials + (size_t)blockIdx.x * NQ1);
}

// ---------------- skeleton pooling kernels (2 volumes per launch) ----------------
// eroded = minpool3x3x3(x)  (pad never wins: min over valid neighbors)

__global__ void erode_kernel(const float* __restrict__ xbuf,
                             float* __restrict__ er)
{
    int tid = blockIdx.x * blockDim.x + threadIdx.x;   // 2,048,000 threads
    int w4  = tid % 40;
    int t2  = tid / 40;
    int h   = t2 % HDIM;
    int t3  = t2 / HDIM;
    int d   = t3 % DDIM;
    int vol = t3 / DDIM;                                // 0..1
    const float* src = xbuf + (size_t)vol * DHW;
    float*       dst = er   + (size_t)vol * DHW;
    int w0 = w4 * 4;

    float r0 = INFINITY, r1 = INFINITY, r2 = INFINITY, r3 = INFINITY;
    #pragma unroll
    for (int dd = -1; dd <= 1; ++dd) {
        int z = d + dd; if ((unsigned)z >= (unsigned)DDIM) continue;
        #pragma unroll
        for (int dh = -1; dh <= 1; ++dh) {
            int y = h + dh; if ((unsigned)y >= (unsigned)HDIM) continue;
            const float* row = src + ((size_t)z * HDIM + y) * WDIM;
            float4 f = *(const float4*)(row + w0);
            float lft = (w0 > 0)            ? row[w0 - 1] : INFINITY;
            float rgt = (w0 + 4 < WDIM)     ? row[w0 + 4] : INFINITY;
            r0 = fminf(r0, fminf(lft, fminf(f.x, f.y)));
            r1 = fminf(r1, fminf(f.x, fminf(f.y, f.z)));
            r2 = fminf(r2, fminf(f.y, fminf(f.z, f.w)));
            r3 = fminf(r3, fminf(f.z, fminf(f.w, rgt)));
        }
    }
    *(float4*)(dst + ((size_t)d * HDIM + h) * WDIM + w0) = make_float4(r0, r1, r2, r3);
}

// opened = maxpool3x3x3(eroded); contour = relu(opened - eroded); x = relu(x - contour)
__global__ void open_update_kernel(float* __restrict__ xbuf,
                                   const float* __restrict__ er)
{
    int tid = blockIdx.x * blockDim.x + threadIdx.x;
    int w4  = tid % 40;
    int t2  = tid / 40;
    int h   = t2 % HDIM;
    int t3  = t2 / HDIM;
    int d   = t3 % DDIM;
    int vol = t3 / DDIM;
    const float* src = er + (size_t)vol * DHW;
    float*       xb  = xbuf + (size_t)vol * DHW;
    int w0 = w4 * 4;

    float o0 = -INFINITY, o1 = -INFINITY, o2 = -INFINITY, o3 = -INFINITY;
    float4 ec = make_float4(0.f, 0.f, 0.f, 0.f);
    #pragma unroll
    for (int dd = -1; dd <= 1; ++dd) {
        int z = d + dd; if ((unsigned)z >= (unsigned)DDIM) continue;
        #pragma unroll
        for (int dh = -1; dh <= 1; ++dh) {
            int y = h + dh; if ((unsigned)y >= (unsigned)HDIM) continue;
            const float* row = src + ((size_t)z * HDIM + y) * WDIM;
            float4 f = *(const float4*)(row + w0);
            float lft = (w0 > 0)        ? row[w0 - 1] : -INFINITY;
            float rgt = (w0 + 4 < WDIM) ? row[w0 + 4] : -INFINITY;
            if (dd == 0 && dh == 0) ec = f;
            o0 = fmaxf(o0, fmaxf(lft, fmaxf(f.x, f.y)));
            o1 = fmaxf(o1, fmaxf(f.x, fmaxf(f.y, f.z)));
            o2 = fmaxf(o2, fmaxf(f.y, fmaxf(f.z, f.w)));
            o3 = fmaxf(o3, fmaxf(f.z, fmaxf(f.w, rgt)));
        }
    }
    size_t idx = ((size_t)d * HDIM + h) * WDIM + w0;
    float4 x = *(float4*)(xb + idx);
    x.x = fmaxf(x.x - fmaxf(o0 - ec.x, 0.0f), 0.0f);
    x.y = fmaxf(x.y - fmaxf(o1 - ec.y, 0.0f), 0.0f);
    x.z = fmaxf(x.z - fmaxf(o2 - ec.z, 0.0f), 0.0f);
    x.w = fmaxf(x.w - fmaxf(o3 - ec.w, 0.0f), 0.0f);
    *(float4*)(xb + idx) = x;
}

// ---------------- final clDice sums ----------------

__global__ void final_reduce_kernel(const float* __restrict__ porig,
                                    const float* __restrict__ pskel,
                                    const float* __restrict__ yskel,
                                    const int*   __restrict__ target,
                                    double* __restrict__ partials)
{
    double acc[NQ2];
    #pragma unroll
    for (int q = 0; q < NQ2; ++q) acc[q] = 0.0;
    // 0 = sum(pskel*yv), 1 = sum(pskel), 2 = sum(yskel*pv), 3 = sum(yskel)

    int tid = blockIdx.x * blockDim.x + threadIdx.x;
    int stride = gridDim.x * blockDim.x;
    for (int g = tid; g < NGRP; g += stride) {
        int i = g * 4;
        float4 ps = *(const float4*)(pskel + i);
        float4 ys = *(const float4*)(yskel + i);
        float4 po = *(const float4*)(porig + i);
        int4   tg = *(const int4*)(target + i);
        const float* psp = (const float*)&ps;
        const float* ysp = (const float*)&ys;
        const float* pop = (const float*)&po;
        const int*   tp  = (const int*)&tg;
        #pragma unroll
        for (int j = 0; j < 4; ++j) {
            float yv = (tp[j] != 0) ? 1.0f : 0.0f;
            acc[0] += (double)(psp[j] * yv);
            acc[1] += (double)psp[j];
            acc[2] += (double)(ysp[j] * pop[j]);
            acc[3] += (double)ysp[j];
        }
    }
    block_reduce_store<NQ2>(acc, partials + (size_t)blockIdx.x * NQ2);
}

// ---------------- finalize: combine partials into the scalar loss ----------------

__global__ void finalize_kernel(const double* __restrict__ p1,
                                const double* __restrict__ p2,
                                float* __restrict__ out)
{
    double acc[NQ1 + NQ2];
    #pragma unroll
    for (int q = 0; q < NQ1 + NQ2; ++q) acc[q] = 0.0;

    for (int b = threadIdx.x; b < NB1; b += 256) {
        #pragma unroll
        for (int q = 0; q < NQ1; ++q) acc[q] += p1[(size_t)b * NQ1 + q];
    }
    for (int b = threadIdx.x; b < NB2; b += 256) {
        #pragma unroll
        for (int q = 0; q < NQ2; ++q) acc[NQ1 + q] += p2[(size_t)b * NQ2 + q];
    }

    __shared__ double smem[NQ1 + NQ2][4];
    int lane = threadIdx.x & 63;
    int wid  = threadIdx.x >> 6;
    #pragma unroll
    for (int q = 0; q < NQ1 + NQ2; ++q) {
        double v = wave_reduce(acc[q]);
        if (lane == 0) smem[q][wid] = v;
    }
    __syncthreads();
    if (threadIdx.x == 0) {
        double a[NQ1 + NQ2];
        #pragma unroll
        for (int q = 0; q < NQ1 + NQ2; ++q)
            a[q] = smem[q][0] + smem[q][1] + smem[q][2] + smem[q][3];

        double ce = a[0] / (double)NVOX;
        double dice = 0.0;
        #pragma unroll
        for (int c = 0; c < 3; ++c) {
            double I = a[1 + c], P = a[4 + c], T = a[7 + c];
            dice += (2.0 * I + SMOOTHF) / (P + T + SMOOTHF);
        }
        dice *= (1.0 / 3.0);
        double base = ce + (1.0 - dice);

        double tprec = a[10] / (a[11] + EPSF);
        double tsens = a[12] / (a[13] + EPSF);
        double cld = 2.0 * tprec * tsens / (tprec + tsens + EPSF);
        out[0] = (float)(base + W_CL * (1.0 - cld));
    }
}

// ---------------- launch ----------------

extern "C" void kernel_launch(void* const* d_in, const int* in_sizes, int n_in,
                              void* d_out, int out_size, void* d_ws, size_t ws_size,
                              hipStream_t stream) {
    const float* logits = (const float*)d_in[0];
    const int*   target = (const int*)d_in[1];

    double* partials1 = (double*)((char*)d_ws + OFF_P1);
    double* partials2 = (double*)((char*)d_ws + OFF_P2);
    float*  porig = (float*)((char*)d_ws + HEADER_BYTES);
    float*  pskel = porig + NVOX;
    float*  yskel = pskel + NVOX;
    float*  er    = yskel + NVOX;   // NVOX floats scratch (reused for p and y)

    init_kernel<<<NB1, 256, 0, stream>>>(logits, target, porig, pskel, yskel, partials1);

    const int pool_blocks = (B_ * DDIM * HDIM * (WDIM / 4)) / 256;  // 8000
    for (int it = 0; it < ITERS; ++it) {
        erode_kernel<<<pool_blocks, 256, 0, stream>>>(pskel, er);
        open_update_kernel<<<pool_blocks, 256, 0, stream>>>(pskel, er);
        erode_kernel<<<pool_blocks, 256, 0, stream>>>(yskel, er);
        open_update_kernel<<<pool_blocks, 256, 0, stream>>>(yskel, er);
    }

    final_reduce_kernel<<<NB2, 256, 0, stream>>>(porig, pskel, yskel, target, partials2);
    finalize_kernel<<<1, 256, 0, stream>>>(partials1, partials2, (float*)d_out);
}

// Round 6
// 965.051 us; speedup vs baseline: 1.6620x; 1.6620x over previous
//
#include <hip/hip_runtime.h>
#include <math.h>

// Problem constants
#define B_    2
#define DDIM  160
#define HDIM  160
#define WDIM  160
#define DHW   (DDIM*HDIM*WDIM)      // 4,096,000
#define NVOX  (B_*DHW)              // 8,192,000
#define NGRP  (NVOX/4)              // 2,048,000 float4 groups
#define ITERS 8

#define SMOOTHF 1e-5
#define EPSF    1e-6
#define W_CL    0.5

// Reduction partials
#define NB1 2048
#define NQ1 10
#define NB2 2048
#define NQ2 4

// Bitpacked y volume: one bit per voxel, rows of 160 bits = 5 words, padded to 8
#define NROWS (B_*DDIM*HDIM)        // 51,200 rows
#define YW    8                     // words per row (5 used, 3 pad)
#define NYW   (NROWS*YW)            // 409,600 words

// ws layout (bytes)
#define OFF_P1 0
#define OFF_P2 (NB1*NQ1*8)          // 163,840
#define HEADER_BYTES 262144         // 256 KiB, 16B aligned

// ---------------- reduction helpers ----------------

__device__ inline double wave_reduce(double v) {
    #pragma unroll
    for (int off = 32; off > 0; off >>= 1)
        v += __shfl_down(v, off, 64);
    return v;
}

template<int NQ>
__device__ inline void block_reduce_store(double* vals, double* out) {
    __shared__ double smem[NQ][4];
    int lane = threadIdx.x & 63;
    int wid  = threadIdx.x >> 6;
    #pragma unroll
    for (int q = 0; q < NQ; ++q) {
        double v = wave_reduce(vals[q]);
        if (lane == 0) smem[q][wid] = v;
    }
    __syncthreads();
    if (threadIdx.x == 0) {
        #pragma unroll
        for (int q = 0; q < NQ; ++q)
            out[q] = smem[q][0] + smem[q][1] + smem[q][2] + smem[q][3];
    }
}

// ---------------- pass 1: softmax / CE / dice partials / p_v ----------------

__global__ void init_kernel(const float* __restrict__ logits,
                            const int*   __restrict__ target,
                            float* __restrict__ porig,
                            float* __restrict__ pskel,
                            double* __restrict__ partials)
{
    double acc[NQ1];
    #pragma unroll
    for (int q = 0; q < NQ1; ++q) acc[q] = 0.0;
    // acc: 0=ce, 1..3=intersect_c, 4..6=pred_sum_c, 7..9=targ_sum_c

    int tid = blockIdx.x * blockDim.x + threadIdx.x;
    int stride = gridDim.x * blockDim.x;
    for (int g = tid; g < NGRP; g += stride) {
        int i = g * 4;
        int b = i / DHW;
        int s = i - b * DHW;
        const float* base = logits + (size_t)b * (3 * DHW) + s;
        float4 l0 = *(const float4*)(base);
        float4 l1 = *(const float4*)(base + DHW);
        float4 l2 = *(const float4*)(base + 2 * DHW);
        int4 tg = *(const int4*)(target + i);

        float pv[4];
        const float* a0 = (const float*)&l0;
        const float* a1 = (const float*)&l1;
        const float* a2 = (const float*)&l2;
        const int*   tt = (const int*)&tg;
        #pragma unroll
        for (int j = 0; j < 4; ++j) {
            float x0 = a0[j], x1 = a1[j], x2 = a2[j];
            float m  = fmaxf(x0, fmaxf(x1, x2));
            float e0 = __expf(x0 - m), e1 = __expf(x1 - m), e2 = __expf(x2 - m);
            float sum = e0 + e1 + e2;
            float inv = 1.0f / sum;
            float q0 = e0 * inv, q1 = e1 * inv, q2 = e2 * inv;
            int t = tt[j];
            float lt = (t == 0) ? x0 : ((t == 1) ? x1 : x2);
            float logp_t = (lt - m) - __logf(sum);
            acc[0] += (double)(-logp_t);
            acc[4] += (double)q0; acc[5] += (double)q1; acc[6] += (double)q2;
            if (t == 0)      { acc[1] += (double)q0; acc[7] += 1.0; }
            else if (t == 1) { acc[2] += (double)q1; acc[8] += 1.0; }
            else             { acc[3] += (double)q2; acc[9] += 1.0; }
            float p = 1.0f - q0;
            pv[j] = fminf(fmaxf(p, 0.0f), 1.0f);
        }
        *(float4*)(porig + i) = make_float4(pv[0], pv[1], pv[2], pv[3]);
        *(float4*)(pskel + i) = make_float4(pv[0], pv[1], pv[2], pv[3]);
    }
    block_reduce_store<NQ1>(acc, partials + (size_t)blockIdx.x * NQ1);
}

// ---------------- y bitpack init ----------------

__global__ void ybits_init(const int* __restrict__ target,
                           unsigned* __restrict__ yb)
{
    int tid = blockIdx.x * 256 + threadIdx.x;   // NYW threads exactly
    int k = tid % YW;
    int rowlin = tid / YW;
    unsigned word = 0u;
    if (k < 5) {
        const int* t = target + (size_t)rowlin * WDIM + k * 32;
        #pragma unroll
        for (int q = 0; q < 8; ++q) {
            int4 v = *(const int4*)(t + q * 4);
            if (v.x) word |= 1u << (q * 4 + 0);
            if (v.y) word |= 1u << (q * 4 + 1);
            if (v.z) word |= 1u << (q * 4 + 2);
            if (v.w) word |= 1u << (q * 4 + 3);
        }
    }
    yb[tid] = word;
}

// ---------------- p-skeleton pooling (float, 16 outputs/thread) ----------------
// eroded = minpool3x3x3 (border-clamped: pad never wins)

__global__ void erode_p(const float* __restrict__ x, float* __restrict__ er)
{
    int tid = blockIdx.x * 256 + threadIdx.x;   // 512,000 threads exactly
    int w16 = tid % 10;
    int t2  = tid / 10;
    int h   = t2 % HDIM;
    int t3  = t2 / HDIM;
    int d   = t3 % DDIM;
    int vol = t3 / DDIM;
    const float* src = x + (size_t)vol * DHW;
    int w0 = w16 * 16;

    float acc[16];
    #pragma unroll
    for (int i = 0; i < 16; ++i) acc[i] = INFINITY;

    #pragma unroll
    for (int dz = -1; dz <= 1; ++dz) {
        int z = d + dz; if ((unsigned)z >= (unsigned)DDIM) continue;
        #pragma unroll
        for (int dy = -1; dy <= 1; ++dy) {
            int y = h + dy; if ((unsigned)y >= (unsigned)HDIM) continue;
            const float* row = src + ((size_t)z * HDIM + y) * WDIM + w0;
            float e[18];
            float4 f;
            f = *(const float4*)(row + 0);  e[1]=f.x;  e[2]=f.y;  e[3]=f.z;  e[4]=f.w;
            f = *(const float4*)(row + 4);  e[5]=f.x;  e[6]=f.y;  e[7]=f.z;  e[8]=f.w;
            f = *(const float4*)(row + 8);  e[9]=f.x;  e[10]=f.y; e[11]=f.z; e[12]=f.w;
            f = *(const float4*)(row + 12); e[13]=f.x; e[14]=f.y; e[15]=f.z; e[16]=f.w;
            e[0]  = (w0 > 0)          ? row[-1] : INFINITY;
            e[17] = (w0 + 16 < WDIM)  ? row[16] : INFINITY;
            #pragma unroll
            for (int i = 0; i < 16; ++i)
                acc[i] = fminf(acc[i], fminf(e[i], fminf(e[i+1], e[i+2])));
        }
    }
    float* dst = er + (size_t)vol * DHW + ((size_t)d * HDIM + h) * WDIM + w0;
    #pragma unroll
    for (int q = 0; q < 4; ++q)
        *(float4*)(dst + q*4) = make_float4(acc[q*4], acc[q*4+1], acc[q*4+2], acc[q*4+3]);
}

// opened = maxpool3x3x3(er); contour = relu(opened - er); x = relu(x - contour)
__global__ void open_update_p(const float* __restrict__ er, float* __restrict__ x)
{
    int tid = blockIdx.x * 256 + threadIdx.x;
    int w16 = tid % 10;
    int t2  = tid / 10;
    int h   = t2 % HDIM;
    int t3  = t2 / HDIM;
    int d   = t3 % DDIM;
    int vol = t3 / DDIM;
    const float* src = er + (size_t)vol * DHW;
    int w0 = w16 * 16;

    float acc[16], ec[16];
    #pragma unroll
    for (int i = 0; i < 16; ++i) acc[i] = -INFINITY;

    #pragma unroll
    for (int dz = -1; dz <= 1; ++dz) {
        int z = d + dz; if ((unsigned)z >= (unsigned)DDIM) continue;
        #pragma unroll
        for (int dy = -1; dy <= 1; ++dy) {
            int y = h + dy; if ((unsigned)y >= (unsigned)HDIM) continue;
            const float* row = src + ((size_t)z * HDIM + y) * WDIM + w0;
            float e[18];
            float4 f;
            f = *(const float4*)(row + 0);  e[1]=f.x;  e[2]=f.y;  e[3]=f.z;  e[4]=f.w;
            f = *(const float4*)(row + 4);  e[5]=f.x;  e[6]=f.y;  e[7]=f.z;  e[8]=f.w;
            f = *(const float4*)(row + 8);  e[9]=f.x;  e[10]=f.y; e[11]=f.z; e[12]=f.w;
            f = *(const float4*)(row + 12); e[13]=f.x; e[14]=f.y; e[15]=f.z; e[16]=f.w;
            e[0]  = (w0 > 0)         ? row[-1] : -INFINITY;
            e[17] = (w0 + 16 < WDIM) ? row[16] : -INFINITY;
            if (dz == 0 && dy == 0) {
                #pragma unroll
                for (int i = 0; i < 16; ++i) ec[i] = e[i+1];
            }
            #pragma unroll
            for (int i = 0; i < 16; ++i)
                acc[i] = fmaxf(acc[i], fmaxf(e[i], fmaxf(e[i+1], e[i+2])));
        }
    }
    float* xb = x + (size_t)vol * DHW + ((size_t)d * HDIM + h) * WDIM + w0;
    #pragma unroll
    for (int q = 0; q < 4; ++q) {
        float4 xv = *(float4*)(xb + q*4);
        float* xs = (float*)&xv;
        #pragma unroll
        for (int j = 0; j < 4; ++j) {
            int i = q*4 + j;
            xs[j] = fmaxf(xs[j] - fmaxf(acc[i] - ec[i], 0.0f), 0.0f);
        }
        *(float4*)(xb + q*4) = xv;
    }
}

// ---------------- y-skeleton (bitpacked) ----------------

__device__ inline void load_yrow(const unsigned* __restrict__ base, unsigned* r) {
    uint4 v = *(const uint4*)base;
    r[0] = v.x; r[1] = v.y; r[2] = v.z; r[3] = v.w; r[4] = base[4];
}

__device__ inline void werode_row(const unsigned* r, unsigned* out) {
    #pragma unroll
    for (int k = 0; k < 5; ++k) {
        unsigned l  = (r[k] << 1) | (k > 0 ? (r[k-1] >> 31) : 1u);
        unsigned rt = (r[k] >> 1) | (k < 4 ? (r[k+1] << 31) : 0x80000000u);
        out[k] = r[k] & l & rt;
    }
}

__device__ inline void wdilate_row(const unsigned* r, unsigned* out) {
    #pragma unroll
    for (int k = 0; k < 5; ++k) {
        unsigned l  = (r[k] << 1) | (k > 0 ? (r[k-1] >> 31) : 0u);
        unsigned rt = (r[k] >> 1) | (k < 4 ? (r[k+1] << 31) : 0u);
        out[k] = r[k] | l | rt;
    }
}

__global__ void y_erode(const unsigned* __restrict__ yb, unsigned* __restrict__ eb)
{
    int tid = blockIdx.x * 256 + threadIdx.x;  // NROWS threads exactly
    int h  = tid % HDIM;
    int t2 = tid / HDIM;
    int d  = t2 % DDIM;
    int b  = t2 / DDIM;
    unsigned acc[5] = {~0u, ~0u, ~0u, ~0u, ~0u};
    #pragma unroll
    for (int dz = -1; dz <= 1; ++dz) {
        int z = d + dz; if ((unsigned)z >= (unsigned)DDIM) continue;
        #pragma unroll
        for (int dy = -1; dy <= 1; ++dy) {
            int y = h + dy; if ((unsigned)y >= (unsigned)HDIM) continue;
            unsigned r[5], we[5];
            load_yrow(yb + ((size_t)(b * DDIM + z) * HDIM + y) * YW, r);
            werode_row(r, we);
            #pragma unroll
            for (int k = 0; k < 5; ++k) acc[k] &= we[k];
        }
    }
    unsigned* o = eb + (size_t)tid * YW;
    *(uint4*)o = make_uint4(acc[0], acc[1], acc[2], acc[3]);
    o[4] = acc[4];
}

__global__ void y_open_update(const unsigned* __restrict__ eb, unsigned* __restrict__ yb)
{
    int tid = blockIdx.x * 256 + threadIdx.x;
    int h  = tid % HDIM;
    int t2 = tid / HDIM;
    int d  = t2 % DDIM;
    int b  = t2 / DDIM;
    unsigned acc[5] = {0u, 0u, 0u, 0u, 0u};
    unsigned ecen[5];
    #pragma unroll
    for (int dz = -1; dz <= 1; ++dz) {
        int z = d + dz; if ((unsigned)z >= (unsigned)DDIM) continue;
        #pragma unroll
        for (int dy = -1; dy <= 1; ++dy) {
            int y = h + dy; if ((unsigned)y >= (unsigned)HDIM) continue;
            unsigned r[5], wd[5];
            load_yrow(eb + ((size_t)(b * DDIM + z) * HDIM + y) * YW, r);
            if (dz == 0 && dy == 0) {
                #pragma unroll
                for (int k = 0; k < 5; ++k) ecen[k] = r[k];
            }
            wdilate_row(r, wd);
            #pragma unroll
            for (int k = 0; k < 5; ++k) acc[k] |= wd[k];
        }
    }
    unsigned* yo = yb + (size_t)tid * YW;
    unsigned yr[5];
    load_yrow(yo, yr);
    unsigned out[5];
    #pragma unroll
    for (int k = 0; k < 5; ++k)
        out[k] = yr[k] & ~(acc[k] & ~ecen[k]);   // x &= ~(opened & ~eroded)
    *(uint4*)yo = make_uint4(out[0], out[1], out[2], out[3]);
    yo[4] = out[4];
}

// ---------------- final clDice sums ----------------

__global__ void final_reduce_kernel(const float* __restrict__ porig,
                                    const float* __restrict__ pskel,
                                    const int*   __restrict__ target,
                                    const unsigned* __restrict__ yb,
                                    double* __restrict__ partials)
{
    double acc[NQ2];
    #pragma unroll
    for (int q = 0; q < NQ2; ++q) acc[q] = 0.0;
    // 0 = sum(pskel*y_v), 1 = sum(pskel), 2 = sum(y_skel*p_v), 3 = sum(y_skel)

    int tid = blockIdx.x * blockDim.x + threadIdx.x;
    int stride = gridDim.x * blockDim.x;
    for (int g = tid; g < NGRP; g += stride) {
        int i = g * 4;
        float4 ps = *(const float4*)(pskel + i);
        float4 po = *(const float4*)(porig + i);
        int4   tg = *(const int4*)(target + i);
        int w = i % WDIM;
        int rowlin = i / WDIM;
        unsigned word = yb[(size_t)rowlin * YW + (w >> 5)];
        unsigned b4 = (word >> (w & 31)) & 0xFu;
        const float* psp = (const float*)&ps;
        const float* pop = (const float*)&po;
        const int*   tp  = (const int*)&tg;
        #pragma unroll
        for (int j = 0; j < 4; ++j) {
            float yv  = (tp[j] != 0) ? 1.0f : 0.0f;
            float ysk = (float)((b4 >> j) & 1u);
            acc[0] += (double)(psp[j] * yv);
            acc[1] += (double)psp[j];
            acc[2] += (double)(ysk * pop[j]);
            acc[3] += (double)ysk;
        }
    }
    block_reduce_store<NQ2>(acc, partials + (size_t)blockIdx.x * NQ2);
}

// ---------------- finalize ----------------

__global__ void finalize_kernel(const double* __restrict__ p1,
                                const double* __restrict__ p2,
                                float* __restrict__ out)
{
    double acc[NQ1 + NQ2];
    #pragma unroll
    for (int q = 0; q < NQ1 + NQ2; ++q) acc[q] = 0.0;

    for (int b = threadIdx.x; b < NB1; b += 256) {
        #pragma unroll
        for (int q = 0; q < NQ1; ++q) acc[q] += p1[(size_t)b * NQ1 + q];
    }
    for (int b = threadIdx.x; b < NB2; b += 256) {
        #pragma unroll
        for (int q = 0; q < NQ2; ++q) acc[NQ1 + q] += p2[(size_t)b * NQ2 + q];
    }

    __shared__ double smem[NQ1 + NQ2][4];
    int lane = threadIdx.x & 63;
    int wid  = threadIdx.x >> 6;
    #pragma unroll
    for (int q = 0; q < NQ1 + NQ2; ++q) {
        double v = wave_reduce(acc[q]);
        if (lane == 0) smem[q][wid] = v;
    }
    __syncthreads();
    if (threadIdx.x == 0) {
        double a[NQ1 + NQ2];
        #pragma unroll
        for (int q = 0; q < NQ1 + NQ2; ++q)
            a[q] = smem[q][0] + smem[q][1] + smem[q][2] + smem[q][3];

        double ce = a[0] / (double)NVOX;
        double dice = 0.0;
        #pragma unroll
        for (int c = 0; c < 3; ++c) {
            double I = a[1 + c], P = a[4 + c], T = a[7 + c];
            dice += (2.0 * I + SMOOTHF) / (P + T + SMOOTHF);
        }
        dice *= (1.0 / 3.0);
        double base = ce + (1.0 - dice);

        double tprec = a[10] / (a[11] + EPSF);
        double tsens = a[12] / (a[13] + EPSF);
        double cld = 2.0 * tprec * tsens / (tprec + tsens + EPSF);
        out[0] = (float)(base + W_CL * (1.0 - cld));
    }
}

// ---------------- launch ----------------

extern "C" void kernel_launch(void* const* d_in, const int* in_sizes, int n_in,
                              void* d_out, int out_size, void* d_ws, size_t ws_size,
                              hipStream_t stream) {
    const float* logits = (const float*)d_in[0];
    const int*   target = (const int*)d_in[1];

    double* partials1 = (double*)((char*)d_ws + OFF_P1);
    double* partials2 = (double*)((char*)d_ws + OFF_P2);
    float*  porig = (float*)((char*)d_ws + HEADER_BYTES);
    float*  pskel = porig + NVOX;
    float*  er    = pskel + NVOX;
    unsigned* ybits  = (unsigned*)(er + NVOX);
    unsigned* yebits = ybits + NYW;

    init_kernel<<<NB1, 256, 0, stream>>>(logits, target, porig, pskel, partials1);
    ybits_init<<<NYW / 256, 256, 0, stream>>>(target, ybits);

    const int pool_blocks = (B_ * DDIM * HDIM * (WDIM / 16)) / 256;  // 2000
    const int yrow_blocks = NROWS / 256;                              // 200
    for (int it = 0; it < ITERS; ++it) {
        erode_p<<<pool_blocks, 256, 0, stream>>>(pskel, er);
        open_update_p<<<pool_blocks, 256, 0, stream>>>(er, pskel);
        y_erode<<<yrow_blocks, 256, 0, stream>>>(ybits, yebits);
        y_open_update<<<yrow_blocks, 256, 0, stream>>>(yebits, ybits);
    }

    final_reduce_kernel<<<NB2, 256, 0, stream>>>(porig, pskel, target, ybits, partials2);
    finalize_kernel<<<1, 256, 0, stream>>>(partials1, partials2, (float*)d_out);
}

// Round 7
// 656.300 us; speedup vs baseline: 2.4438x; 1.4704x over previous
//
#include <hip/hip_runtime.h>
#include <math.h>

// Problem constants
#define B_    2
#define DDIM  160
#define HDIM  160
#define WDIM  160
#define DHW   (DDIM*HDIM*WDIM)      // 4,096,000
#define NVOX  (B_*DHW)              // 8,192,000
#define NGRP  (NVOX/4)              // 2,048,000 float4 groups
#define ITERS 8
#define DT    4                     // d-outputs per pool thread

#define SMOOTHF 1e-5
#define EPSF    1e-6
#define W_CL    0.5

// Reduction partials
#define NB1 2048
#define NQ1 10
#define NB2 2048
#define NQ2 4

// Bitpacked y volume: one bit per voxel, rows of 160 bits = 5 words, padded to 8
#define NROWS (B_*DDIM*HDIM)        // 51,200 rows
#define YW    8                     // words per row (5 used, 3 pad)
#define NYW   (NROWS*YW)            // 409,600 words

// Fused pool grid: p-blocks then y-blocks
#define P_THREADS (10*HDIM*(DDIM/DT)*B_)   // 128,000
#define P_BLOCKS  (P_THREADS/256)          // 500
#define Y_BLOCKS  (NROWS/256)              // 200
#define F_BLOCKS  (P_BLOCKS + Y_BLOCKS)    // 700

// ws layout (bytes)
#define OFF_P1 0
#define OFF_P2 (NB1*NQ1*8)          // 163,840
#define HEADER_BYTES 262144         // 256 KiB, 16B aligned

// ---------------- reduction helpers ----------------

__device__ inline double wave_reduce(double v) {
    #pragma unroll
    for (int off = 32; off > 0; off >>= 1)
        v += __shfl_down(v, off, 64);
    return v;
}

template<int NQ>
__device__ inline void block_reduce_store(double* vals, double* out) {
    __shared__ double smem[NQ][4];
    int lane = threadIdx.x & 63;
    int wid  = threadIdx.x >> 6;
    #pragma unroll
    for (int q = 0; q < NQ; ++q) {
        double v = wave_reduce(vals[q]);
        if (lane == 0) smem[q][wid] = v;
    }
    __syncthreads();
    if (threadIdx.x == 0) {
        #pragma unroll
        for (int q = 0; q < NQ; ++q)
            out[q] = smem[q][0] + smem[q][1] + smem[q][2] + smem[q][3];
    }
}

// ---------------- pass 1: softmax / CE / dice partials / p_v ----------------

__global__ void init_kernel(const float* __restrict__ logits,
                            const int*   __restrict__ target,
                            float* __restrict__ porig,
                            double* __restrict__ partials)
{
    double acc[NQ1];
    #pragma unroll
    for (int q = 0; q < NQ1; ++q) acc[q] = 0.0;
    // acc: 0=ce, 1..3=intersect_c, 4..6=pred_sum_c, 7..9=targ_sum_c

    int tid = blockIdx.x * blockDim.x + threadIdx.x;
    int stride = gridDim.x * blockDim.x;
    for (int g = tid; g < NGRP; g += stride) {
        int i = g * 4;
        int b = i / DHW;
        int s = i - b * DHW;
        const float* base = logits + (size_t)b * (3 * DHW) + s;
        float4 l0 = *(const float4*)(base);
        float4 l1 = *(const float4*)(base + DHW);
        float4 l2 = *(const float4*)(base + 2 * DHW);
        int4 tg = *(const int4*)(target + i);

        float pv[4];
        const float* a0 = (const float*)&l0;
        const float* a1 = (const float*)&l1;
        const float* a2 = (const float*)&l2;
        const int*   tt = (const int*)&tg;
        #pragma unroll
        for (int j = 0; j < 4; ++j) {
            float x0 = a0[j], x1 = a1[j], x2 = a2[j];
            float m  = fmaxf(x0, fmaxf(x1, x2));
            float e0 = __expf(x0 - m), e1 = __expf(x1 - m), e2 = __expf(x2 - m);
            float sum = e0 + e1 + e2;
            float inv = 1.0f / sum;
            float q0 = e0 * inv, q1 = e1 * inv, q2 = e2 * inv;
            int t = tt[j];
            float lt = (t == 0) ? x0 : ((t == 1) ? x1 : x2);
            float logp_t = (lt - m) - __logf(sum);
            acc[0] += (double)(-logp_t);
            acc[4] += (double)q0; acc[5] += (double)q1; acc[6] += (double)q2;
            if (t == 0)      { acc[1] += (double)q0; acc[7] += 1.0; }
            else if (t == 1) { acc[2] += (double)q1; acc[8] += 1.0; }
            else             { acc[3] += (double)q2; acc[9] += 1.0; }
            float p = 1.0f - q0;
            pv[j] = fminf(fmaxf(p, 0.0f), 1.0f);
        }
        *(float4*)(porig + i) = make_float4(pv[0], pv[1], pv[2], pv[3]);
    }
    block_reduce_store<NQ1>(acc, partials + (size_t)blockIdx.x * NQ1);
}

// ---------------- y bitpack init ----------------

__global__ void ybits_init(const int* __restrict__ target,
                           unsigned* __restrict__ yb)
{
    int tid = blockIdx.x * 256 + threadIdx.x;   // NYW threads exactly
    int k = tid % YW;
    int rowlin = tid / YW;
    unsigned word = 0u;
    if (k < 5) {
        const int* t = target + (size_t)rowlin * WDIM + k * 32;
        #pragma unroll
        for (int q = 0; q < 8; ++q) {
            int4 v = *(const int4*)(t + q * 4);
            if (v.x) word |= 1u << (q * 4 + 0);
            if (v.y) word |= 1u << (q * 4 + 1);
            if (v.z) word |= 1u << (q * 4 + 2);
            if (v.w) word |= 1u << (q * 4 + 3);
        }
    }
    yb[tid] = word;
}

// ---------------- helpers ----------------

// 18-wide row window [w0-1, w0+16], border filled with pad
__device__ inline void row18(const float* __restrict__ row, int w0, float pad, float* e) {
    float4 f;
    f = *(const float4*)(row + 0);  e[1]=f.x;  e[2]=f.y;  e[3]=f.z;  e[4]=f.w;
    f = *(const float4*)(row + 4);  e[5]=f.x;  e[6]=f.y;  e[7]=f.z;  e[8]=f.w;
    f = *(const float4*)(row + 8);  e[9]=f.x;  e[10]=f.y; e[11]=f.z; e[12]=f.w;
    f = *(const float4*)(row + 12); e[13]=f.x; e[14]=f.y; e[15]=f.z; e[16]=f.w;
    e[0]  = (w0 > 0)         ? row[-1] : pad;
    e[17] = (w0 + 16 < WDIM) ? row[16] : pad;
}

__device__ inline void load_yrow(const unsigned* __restrict__ base, unsigned* r) {
    uint4 v = *(const uint4*)base;
    r[0] = v.x; r[1] = v.y; r[2] = v.z; r[3] = v.w; r[4] = base[4];
}

__device__ inline void werode_row(const unsigned* r, unsigned* out) {
    #pragma unroll
    for (int k = 0; k < 5; ++k) {
        unsigned l  = (r[k] << 1) | (k > 0 ? (r[k-1] >> 31) : 1u);
        unsigned rt = (r[k] >> 1) | (k < 4 ? (r[k+1] << 31) : 0x80000000u);
        out[k] = r[k] & l & rt;
    }
}

__device__ inline void wdilate_row(const unsigned* r, unsigned* out) {
    #pragma unroll
    for (int k = 0; k < 5; ++k) {
        unsigned l  = (r[k] << 1) | (k > 0 ? (r[k-1] >> 31) : 0u);
        unsigned rt = (r[k] >> 1) | (k < 4 ? (r[k+1] << 31) : 0u);
        out[k] = r[k] | l | rt;
    }
}

// ---------------- fused erode (p float DT-brick + y bitrows) ----------------
// p: eroded = minpool3x3x3(x), separable minW->minH->minD, ring over d.

__global__ void fused_erode(const float* __restrict__ x, float* __restrict__ er,
                            const unsigned* __restrict__ yb, unsigned* __restrict__ eb)
{
    if (blockIdx.x < P_BLOCKS) {
        int tid = blockIdx.x * 256 + threadIdx.x;   // 0..127,999
        int w16 = tid % 10;
        int t2  = tid / 10;
        int h   = t2 % HDIM;
        int t3  = t2 / HDIM;
        int dc  = t3 % (DDIM / DT);
        int vol = t3 / (DDIM / DT);
        int w0  = w16 * 16;
        int d0  = dc * DT;
        const float* src = x + (size_t)vol * DHW;
        float*       dst = er + (size_t)vol * DHW;

        float ring[3][16];
        #pragma unroll
        for (int step = 0; step < DT + 2; ++step) {
            int d = d0 - 1 + step;
            float cur[16];
            #pragma unroll
            for (int i = 0; i < 16; ++i) cur[i] = INFINITY;
            if ((unsigned)d < (unsigned)DDIM) {
                #pragma unroll
                for (int dy = -1; dy <= 1; ++dy) {
                    int y = h + dy;
                    if ((unsigned)y >= (unsigned)HDIM) continue;
                    const float* row = src + ((size_t)d * HDIM + y) * WDIM + w0;
                    float e[18];
                    row18(row, w0, INFINITY, e);
                    #pragma unroll
                    for (int i = 0; i < 16; ++i)
                        cur[i] = fminf(cur[i], fminf(e[i], fminf(e[i+1], e[i+2])));
                }
            }
            #pragma unroll
            for (int i = 0; i < 16; ++i) ring[step % 3][i] = cur[i];
            if (step >= 2) {
                int dd = d - 1;                      // output plane d0..d0+DT-1
                float* o = dst + ((size_t)dd * HDIM + h) * WDIM + w0;
                #pragma unroll
                for (int q = 0; q < 4; ++q) {
                    float4 v;
                    v.x = fminf(ring[0][q*4+0], fminf(ring[1][q*4+0], ring[2][q*4+0]));
                    v.y = fminf(ring[0][q*4+1], fminf(ring[1][q*4+1], ring[2][q*4+1]));
                    v.z = fminf(ring[0][q*4+2], fminf(ring[1][q*4+2], ring[2][q*4+2]));
                    v.w = fminf(ring[0][q*4+3], fminf(ring[1][q*4+3], ring[2][q*4+3]));
                    *(float4*)(o + q*4) = v;
                }
            }
        }
    } else {
        int tid = (blockIdx.x - P_BLOCKS) * 256 + threadIdx.x;  // 0..51,199
        int h  = tid % HDIM;
        int t2 = tid / HDIM;
        int d  = t2 % DDIM;
        int b  = t2 / DDIM;
        unsigned acc[5] = {~0u, ~0u, ~0u, ~0u, ~0u};
        #pragma unroll
        for (int dz = -1; dz <= 1; ++dz) {
            int z = d + dz; if ((unsigned)z >= (unsigned)DDIM) continue;
            #pragma unroll
            for (int dy = -1; dy <= 1; ++dy) {
                int y = h + dy; if ((unsigned)y >= (unsigned)HDIM) continue;
                unsigned r[5], we[5];
                load_yrow(yb + ((size_t)(b * DDIM + z) * HDIM + y) * YW, r);
                werode_row(r, we);
                #pragma unroll
                for (int k = 0; k < 5; ++k) acc[k] &= we[k];
            }
        }
        unsigned* o = eb + (size_t)tid * YW;
        *(uint4*)o = make_uint4(acc[0], acc[1], acc[2], acc[3]);
        o[4] = acc[4];
    }
}

// ---------------- fused open+update (p float DT-brick + y bitrows) ----------------
// opened = maxpool3x3x3(er); x = relu(x - relu(opened - er))

__global__ void fused_open(const float* __restrict__ er,
                           const float* __restrict__ xsrc, float* __restrict__ xdst,
                           const unsigned* __restrict__ eb, unsigned* __restrict__ yb)
{
    if (blockIdx.x < P_BLOCKS) {
        int tid = blockIdx.x * 256 + threadIdx.x;
        int w16 = tid % 10;
        int t2  = tid / 10;
        int h   = t2 % HDIM;
        int t3  = t2 / HDIM;
        int dc  = t3 % (DDIM / DT);
        int vol = t3 / (DDIM / DT);
        int w0  = w16 * 16;
        int d0  = dc * DT;
        const float* ers = er + (size_t)vol * DHW;
        const float* xs  = xsrc + (size_t)vol * DHW;
        float*       xb  = xdst + (size_t)vol * DHW;

        float ring[3][16];
        #pragma unroll
        for (int step = 0; step < DT + 2; ++step) {
            int d = d0 - 1 + step;
            float cur[16];
            #pragma unroll
            for (int i = 0; i < 16; ++i) cur[i] = -INFINITY;
            if ((unsigned)d < (unsigned)DDIM) {
                #pragma unroll
                for (int dy = -1; dy <= 1; ++dy) {
                    int y = h + dy;
                    if ((unsigned)y >= (unsigned)HDIM) continue;
                    const float* row = ers + ((size_t)d * HDIM + y) * WDIM + w0;
                    float e[18];
                    row18(row, w0, -INFINITY, e);
                    #pragma unroll
                    for (int i = 0; i < 16; ++i)
                        cur[i] = fmaxf(cur[i], fmaxf(e[i], fmaxf(e[i+1], e[i+2])));
                }
            }
            #pragma unroll
            for (int i = 0; i < 16; ++i) ring[step % 3][i] = cur[i];
            if (step >= 2) {
                int dd = d - 1;
                size_t idx = ((size_t)dd * HDIM + h) * WDIM + w0;
                #pragma unroll
                for (int q = 0; q < 4; ++q) {
                    float4 ec = *(const float4*)(ers + idx + q*4);
                    float4 xv = *(const float4*)(xs + idx + q*4);
                    float o0 = fmaxf(ring[0][q*4+0], fmaxf(ring[1][q*4+0], ring[2][q*4+0]));
                    float o1 = fmaxf(ring[0][q*4+1], fmaxf(ring[1][q*4+1], ring[2][q*4+1]));
                    float o2 = fmaxf(ring[0][q*4+2], fmaxf(ring[1][q*4+2], ring[2][q*4+2]));
                    float o3 = fmaxf(ring[0][q*4+3], fmaxf(ring[1][q*4+3], ring[2][q*4+3]));
                    float4 r;
                    r.x = fmaxf(xv.x - fmaxf(o0 - ec.x, 0.0f), 0.0f);
                    r.y = fmaxf(xv.y - fmaxf(o1 - ec.y, 0.0f), 0.0f);
                    r.z = fmaxf(xv.z - fmaxf(o2 - ec.z, 0.0f), 0.0f);
                    r.w = fmaxf(xv.w - fmaxf(o3 - ec.w, 0.0f), 0.0f);
                    *(float4*)(xb + idx + q*4) = r;
                }
            }
        }
    } else {
        int tid = (blockIdx.x - P_BLOCKS) * 256 + threadIdx.x;
        int h  = tid % HDIM;
        int t2 = tid / HDIM;
        int d  = t2 % DDIM;
        int b  = t2 / DDIM;
        unsigned acc[5] = {0u, 0u, 0u, 0u, 0u};
        unsigned ecen[5];
        #pragma unroll
        for (int dz = -1; dz <= 1; ++dz) {
            int z = d + dz; if ((unsigned)z >= (unsigned)DDIM) continue;
            #pragma unroll
            for (int dy = -1; dy <= 1; ++dy) {
                int y = h + dy; if ((unsigned)y >= (unsigned)HDIM) continue;
                unsigned r[5], wd[5];
                load_yrow(eb + ((size_t)(b * DDIM + z) * HDIM + y) * YW, r);
                if (dz == 0 && dy == 0) {
                    #pragma unroll
                    for (int k = 0; k < 5; ++k) ecen[k] = r[k];
                }
                wdilate_row(r, wd);
                #pragma unroll
                for (int k = 0; k < 5; ++k) acc[k] |= wd[k];
            }
        }
        unsigned* yo = yb + (size_t)tid * YW;
        unsigned yr[5];
        load_yrow(yo, yr);
        unsigned out[5];
        #pragma unroll
        for (int k = 0; k < 5; ++k)
            out[k] = yr[k] & ~(acc[k] & ~ecen[k]);   // x &= ~(opened & ~eroded)
        *(uint4*)yo = make_uint4(out[0], out[1], out[2], out[3]);
        yo[4] = out[4];
    }
}

// ---------------- final clDice sums ----------------

__global__ void final_reduce_kernel(const float* __restrict__ porig,
                                    const float* __restrict__ pskel,
                                    const int*   __restrict__ target,
                                    const unsigned* __restrict__ yb,
                                    double* __restrict__ partials)
{
    double acc[NQ2];
    #pragma unroll
    for (int q = 0; q < NQ2; ++q) acc[q] = 0.0;
    // 0 = sum(pskel*y_v), 1 = sum(pskel), 2 = sum(y_skel*p_v), 3 = sum(y_skel)

    int tid = blockIdx.x * blockDim.x + threadIdx.x;
    int stride = gridDim.x * blockDim.x;
    for (int g = tid; g < NGRP; g += stride) {
        int i = g * 4;
        float4 ps = *(const float4*)(pskel + i);
        float4 po = *(const float4*)(porig + i);
        int4   tg = *(const int4*)(target + i);
        int w = i % WDIM;
        int rowlin = i / WDIM;
        unsigned word = yb[(size_t)rowlin * YW + (w >> 5)];
        unsigned b4 = (word >> (w & 31)) & 0xFu;
        const float* psp = (const float*)&ps;
        const float* pop = (const float*)&po;
        const int*   tp  = (const int*)&tg;
        #pragma unroll
        for (int j = 0; j < 4; ++j) {
            float yv  = (tp[j] != 0) ? 1.0f : 0.0f;
            float ysk = (float)((b4 >> j) & 1u);
            acc[0] += (double)(psp[j] * yv);
            acc[1] += (double)psp[j];
            acc[2] += (double)(ysk * pop[j]);
            acc[3] += (double)ysk;
        }
    }
    block_reduce_store<NQ2>(acc, partials + (size_t)blockIdx.x * NQ2);
}

// ---------------- finalize ----------------

__global__ void finalize_kernel(const double* __restrict__ p1,
                                const double* __restrict__ p2,
                                float* __restrict__ out)
{
    double acc[NQ1 + NQ2];
    #pragma unroll
    for (int q = 0; q < NQ1 + NQ2; ++q) acc[q] = 0.0;

    for (int b = threadIdx.x; b < NB1; b += 256) {
        #pragma unroll
        for (int q = 0; q < NQ1; ++q) acc[q] += p1[(size_t)b * NQ1 + q];
    }
    for (int b = threadIdx.x; b < NB2; b += 256) {
        #pragma unroll
        for (int q = 0; q < NQ2; ++q) acc[NQ1 + q] += p2[(size_t)b * NQ2 + q];
    }

    __shared__ double smem[NQ1 + NQ2][4];
    int lane = threadIdx.x & 63;
    int wid  = threadIdx.x >> 6;
    #pragma unroll
    for (int q = 0; q < NQ1 + NQ2; ++q) {
        double v = wave_reduce(acc[q]);
        if (lane == 0) smem[q][wid] = v;
    }
    __syncthreads();
    if (threadIdx.x == 0) {
        double a[NQ1 + NQ2];
        #pragma unroll
        for (int q = 0; q < NQ1 + NQ2; ++q)
            a[q] = smem[q][0] + smem[q][1] + smem[q][2] + smem[q][3];

        double ce = a[0] / (double)NVOX;
        double dice = 0.0;
        #pragma unroll
        for (int c = 0; c < 3; ++c) {
            double I = a[1 + c], P = a[4 + c], T = a[7 + c];
            dice += (2.0 * I + SMOOTHF) / (P + T + SMOOTHF);
        }
        dice *= (1.0 / 3.0);
        double base = ce + (1.0 - dice);

        double tprec = a[10] / (a[11] + EPSF);
        double tsens = a[12] / (a[13] + EPSF);
        double cld = 2.0 * tprec * tsens / (tprec + tsens + EPSF);
        out[0] = (float)(base + W_CL * (1.0 - cld));
    }
}

// ---------------- launch ----------------

extern "C" void kernel_launch(void* const* d_in, const int* in_sizes, int n_in,
                              void* d_out, int out_size, void* d_ws, size_t ws_size,
                              hipStream_t stream) {
    const float* logits = (const float*)d_in[0];
    const int*   target = (const int*)d_in[1];

    double* partials1 = (double*)((char*)d_ws + OFF_P1);
    double* partials2 = (double*)((char*)d_ws + OFF_P2);
    float*  porig = (float*)((char*)d_ws + HEADER_BYTES);
    float*  pskel = porig + NVOX;
    float*  er    = pskel + NVOX;
    unsigned* ybits  = (unsigned*)(er + NVOX);
    unsigned* yebits = ybits + NYW;

    init_kernel<<<NB1, 256, 0, stream>>>(logits, target, porig, partials1);
    ybits_init<<<NYW / 256, 256, 0, stream>>>(target, ybits);

    for (int it = 0; it < ITERS; ++it) {
        const float* xsrc = (it == 0) ? porig : pskel;
        fused_erode<<<F_BLOCKS, 256, 0, stream>>>(xsrc, er, ybits, yebits);
        fused_open<<<F_BLOCKS, 256, 0, stream>>>(er, xsrc, pskel, yebits, ybits);
    }

    final_reduce_kernel<<<NB2, 256, 0, stream>>>(porig, pskel, target, ybits, partials2);
    finalize_kernel<<<1, 256, 0, stream>>>(partials1, partials2, (float*)d_out);
}